// Round 5
// baseline (327.104 us; speedup 1.0000x reference)
//
#include <hip/hip_runtime.h>

#define INSZ   2048
#define NH1    256
#define NH2    64
#define NB     8
#define BATCH  16384

#define TS        32                 // rows per block-tile
#define MAXTILES  (BATCH / TS)       // 512 (worst case: all samples in one bucket)
#define GRIDX     (NB * MAXTILES)    // 4096, bkt = blockIdx & 7 -> XCD pin

// W1f: [bkt][kb(64)][cg(16)][lane(64)][8] bf16
#define W1F_U4   (NB * 64 * 16 * 64)        // 524288 uint4
#define W2F_U4   (NB * 8 * 4 * 64)          // 16384 uint4

// ws layout (bytes)
#define META_OFF  0                  // 32 ints: cnt[8], off[8], cursor[8]
#define ORDER_OFF 1024               // 16384 ints
#define W1F_OFF   (1024 + BATCH * 4)            // 66560
#define W2F_OFF   (W1F_OFF + W1F_U4 * 16)       // 8,455,168
#define WS_NEED   (W2F_OFF + W2F_U4 * 16)       // 8,717,312

typedef float f4  __attribute__((ext_vector_type(4)));
typedef float f32x4 __attribute__((ext_vector_type(4)));
typedef short bf16x8 __attribute__((ext_vector_type(8)));

__device__ __forceinline__ unsigned short f2bf(float f) {
    unsigned u = __float_as_uint(f);
    u += 0x7fffu + ((u >> 16) & 1u);   // RNE
    return (unsigned short)(u >> 16);
}
__device__ __forceinline__ float clamp01(float v) { return fminf(fmaxf(v, 0.0f), 1.0f); }
__device__ __forceinline__ unsigned pack2(float a, float b) {
    return (unsigned)f2bf(a) | ((unsigned)f2bf(b) << 16);
}
__device__ __forceinline__ bf16x8 cvt8(f4 lo, f4 hi) {
    union { bf16x8 v; unsigned u[4]; } r;
    r.u[0] = pack2(lo[0], lo[1]); r.u[1] = pack2(lo[2], lo[3]);
    r.u[2] = pack2(hi[0], hi[1]); r.u[3] = pack2(hi[2], hi[3]);
    return r.v;
}

// ============================ pre-pass kernels ============================

__global__ void k_countscan(const int* __restrict__ idx, int* __restrict__ meta) {
    __shared__ int scnt[NB];
    int t = threadIdx.x;
    if (t < NB) scnt[t] = 0;
    __syncthreads();
    int local[NB];
#pragma unroll
    for (int bb = 0; bb < NB; bb++) local[bb] = 0;
    for (int i = t; i < BATCH; i += 1024) {
        int b = idx[i];
#pragma unroll
        for (int bb = 0; bb < NB; bb++) local[bb] += (b == bb) ? 1 : 0;
    }
#pragma unroll
    for (int bb = 0; bb < NB; bb++) {
        int v = local[bb];
        v += __shfl_xor(v, 1);  v += __shfl_xor(v, 2);  v += __shfl_xor(v, 4);
        v += __shfl_xor(v, 8);  v += __shfl_xor(v, 16); v += __shfl_xor(v, 32);
        if ((t & 63) == 0) atomicAdd(&scnt[bb], v);
    }
    __syncthreads();
    if (t == 0) {
        int run = 0;
        for (int b = 0; b < NB; b++) {
            int c = scnt[b];
            meta[b]      = c;
            meta[8 + b]  = run;
            meta[16 + b] = run;   // scatter cursor
            run += c;
        }
    }
}

__global__ void k_scatter(const int* __restrict__ idx, int* __restrict__ meta,
                          int* __restrict__ order) {
    __shared__ int wcnt[16][NB];
    __shared__ int sbase[NB];
    int t = threadIdx.x;
    int i = blockIdx.x * 1024 + t;
    int b = idx[i];
    int wv = t >> 6, lane = t & 63;
    unsigned long long mymask = 0;
#pragma unroll
    for (int bb = 0; bb < NB; bb++) {
        unsigned long long m = __ballot(b == bb);
        if (b == bb) mymask = m;
        if (lane == bb) wcnt[wv][bb] = (int)__popcll(m);
    }
    int myrank = (int)__popcll(mymask & ((1ull << lane) - 1ull));
    __syncthreads();
    if (t < NB) {
        int sum = 0;
        for (int w2 = 0; w2 < 16; w2++) { int c = wcnt[w2][t]; wcnt[w2][t] = sum; sum += c; }
        sbase[t] = atomicAdd(&meta[16 + t], sum);
    }
    __syncthreads();
    order[sbase[b] + wcnt[wv][b] + myrank] = i;
}

// pack W1/W2 into per-lane MFMA B-fragment order (bf16)
__global__ void k_pack(const float* __restrict__ W1, const float* __restrict__ W2,
                       uint4* __restrict__ W1f, uint4* __restrict__ W2f) {
    int u = blockIdx.x * 256 + threadIdx.x;
    if (u < W1F_U4) {
        int lane = u & 63, cg = (u >> 6) & 15, kb = (u >> 10) & 63, bkt = u >> 16;
        int l15 = lane & 15, quad = lane >> 4;
        const float* p = W1 + (size_t)(bkt * NH1 + cg * 16 + l15) * INSZ + kb * 32 + quad * 8;
        f4 lo = *(const f4*)p, hi = *(const f4*)(p + 4);
        uint4 o;
        o.x = pack2(lo[0], lo[1]); o.y = pack2(lo[2], lo[3]);
        o.z = pack2(hi[0], hi[1]); o.w = pack2(hi[2], hi[3]);
        W1f[u] = o;
    } else {
        int v = u - W1F_U4;
        if (v >= W2F_U4) return;
        int lane = v & 63, cg2 = (v >> 6) & 3, kb2 = (v >> 8) & 7, bkt = v >> 11;
        int l15 = lane & 15, quad = lane >> 4;
        const float* p = W2 + (size_t)(bkt * NH2 + cg2 * 16 + l15) * NH1 + kb2 * 32 + quad * 8;
        f4 lo = *(const f4*)p, hi = *(const f4*)(p + 4);
        uint4 o;
        o.x = pack2(lo[0], lo[1]); o.y = pack2(lo[2], lo[3]);
        o.z = pack2(hi[0], hi[1]); o.w = pack2(hi[2], hi[3]);
        W2f[v] = o;
    }
}

// ============================ main fused kernel ============================
// 32 rows x 256 cols per block, 4 waves. Wave (g = w&1, ch = w>>1) owns rows
// g*16..+15 x cols ch*128..+127. ZERO barriers in the K-loop: B-frags per-lane
// from L2-pinned W1f (explicit dbuf bcur/bnext), A-frags per-lane from x with
// 3-step register lookahead. One barrier before layer 2 (sh1 cross-wave).

__global__ __launch_bounds__(256, 3) void fused_v5(
    const float* __restrict__ x, const int* __restrict__ meta,
    const int* __restrict__ order,
    const short* __restrict__ W1f, const short* __restrict__ W2f,
    const float* __restrict__ b1, const float* __restrict__ b2,
    const float* __restrict__ W3, const float* __restrict__ b3,
    float* __restrict__ out)
{
    const int bkt  = blockIdx.x & 7;       // bucket -> XCD pin (round-robin dispatch)
    const int base = (blockIdx.x >> 3) * TS;
    const int cnt  = meta[bkt];
    if (base >= cnt) return;
    const int off = meta[8 + bkt];

    __shared__ short sh1[TS * 260];        // 16.6 KB, 2-way-bank-conflict stride
    __shared__ float sPart[2][TS];

    const int t = threadIdx.x;
    const int lane = t & 63, w = t >> 6;
    const int l15 = lane & 15, quad = lane >> 4;
    const int g = w & 1, ch = w >> 1;      // row-group, col-half

    // A operand: lane (quad,l15) holds row l15 (of this group), k = kb*32+quad*8..+7
    int ii = base + g * 16 + l15; if (ii > cnt - 1) ii = cnt - 1;
    const float* xrp = x + (size_t)order[off + ii] * INSZ + quad * 8;
    // B operand: frag (kb, i) at wp + kb*8192 + i*512 (shorts), i = 0..7 in this col-half
    const short* wp = W1f + ((size_t)bkt << 19) + (size_t)(ch * 8) * 512 + lane * 8;

    f32x4 acc[8];
#pragma unroll
    for (int i = 0; i < 8; i++) acc[i] = (f32x4)0.0f;

    bf16x8 bcur[8], bnext[8];
#pragma unroll
    for (int i = 0; i < 8; i++) bcur[i] = *(const bf16x8*)(wp + i * 512);

    // x lookahead: xa = frag(kb), xb = frag(kb+1), xc = frag(kb+2)
    f4 xa0 = *(const f4*)xrp,        xa1 = *(const f4*)(xrp + 4);
    f4 xb0 = *(const f4*)(xrp + 32), xb1 = *(const f4*)(xrp + 36);
    f4 xc0 = *(const f4*)(xrp + 64), xc1 = *(const f4*)(xrp + 68);

#pragma unroll 2
    for (int kb = 0; kb < 64; kb++) {
        if (kb < 63) {
            const short* np = wp + (size_t)(kb + 1) * 8192;
#pragma unroll
            for (int i = 0; i < 8; i++) bnext[i] = *(const bf16x8*)(np + i * 512);
        }
        bf16x8 a = cvt8(xa0, xa1);
        xa0 = xb0; xa1 = xb1;
        xb0 = xc0; xb1 = xc1;
        if (kb < 61) {
            xc0 = *(const f4*)(xrp + (kb + 3) * 32);
            xc1 = *(const f4*)(xrp + (kb + 3) * 32 + 4);
        }
#pragma unroll
        for (int i = 0; i < 8; i++)
            acc[i] = __builtin_amdgcn_mfma_f32_16x16x32_bf16(a, bcur[i], acc[i], 0, 0, 0);
#pragma unroll
        for (int i = 0; i < 8; i++) bcur[i] = bnext[i];
    }

    // layer-1 epilogue: bias + clip01 -> sh1 (bf16, stride 260)
#pragma unroll
    for (int i = 0; i < 8; i++) {
        int col = (ch * 8 + i) * 16 + l15;
        float bias = b1[bkt * NH1 + col];
#pragma unroll
        for (int r = 0; r < 4; r++) {
            int row = g * 16 + quad * 4 + r;
            sh1[row * 260 + col] = (short)f2bf(clamp01(acc[i][r] + bias));
        }
    }
    __syncthreads();

    // layer 2: wave (g,ch) -> rows g*16..+15, h2 cols (ch*2+{0,1})*16..+15
    f32x4 c2[2];
    c2[0] = (f32x4)0.0f; c2[1] = (f32x4)0.0f;
    const short* w2p = W2f + (size_t)bkt * 16384 + lane * 8;
#pragma unroll
    for (int kb2 = 0; kb2 < 8; kb2++) {
        bf16x8 a2 = *(const bf16x8*)&sh1[(g * 16 + l15) * 260 + kb2 * 32 + quad * 8];
#pragma unroll
        for (int j = 0; j < 2; j++) {
            bf16x8 bw = *(const bf16x8*)(w2p + (kb2 * 4 + ch * 2 + j) * 512);
            c2[j] = __builtin_amdgcn_mfma_f32_16x16x32_bf16(a2, bw, c2[j], 0, 0, 0);
        }
    }

    // layer-2 epilogue + layer-3 partial dot (32 of 64 cols per wave)
    float s[4] = {0, 0, 0, 0};
#pragma unroll
    for (int j = 0; j < 2; j++) {
        int n2 = (ch * 2 + j) * 16 + l15;
        float bias2 = b2[bkt * NH2 + n2];
        float w3v   = W3[bkt * NH2 + n2];
#pragma unroll
        for (int r = 0; r < 4; r++)
            s[r] += clamp01(c2[j][r] + bias2) * w3v;
    }
#pragma unroll
    for (int r = 0; r < 4; r++) {
        float pp = s[r];
        pp += __shfl_xor(pp, 1); pp += __shfl_xor(pp, 2);
        pp += __shfl_xor(pp, 4); pp += __shfl_xor(pp, 8);
        if (l15 == 0) sPart[ch][g * 16 + quad * 4 + r] = pp;
    }
    __syncthreads();
    if (t < TS && base + t < cnt)
        out[order[off + base + t]] = sPart[0][t] + sPart[1][t] + b3[bkt];
}

// ============================ naive fallback ============================

__global__ void naive_mlp(const float* __restrict__ x, const int* __restrict__ idx,
                          const float* __restrict__ W1, const float* __restrict__ b1,
                          const float* __restrict__ W2, const float* __restrict__ b2,
                          const float* __restrict__ W3, const float* __restrict__ b3,
                          float* __restrict__ out)
{
    int i = blockIdx.x;
    int b = idx[i];
    __shared__ float sx[INSZ];
    __shared__ float sh1n[NH1];
    __shared__ float sh2n[NH2];
    for (int t = threadIdx.x; t < INSZ; t += 256) sx[t] = x[(size_t)i * INSZ + t];
    __syncthreads();
    int j = threadIdx.x;
    {
        const float* wr = W1 + (size_t)(b * NH1 + j) * INSZ;
        float acc = b1[b * NH1 + j];
        for (int k = 0; k < INSZ; k++) acc += sx[k] * wr[k];
        sh1n[j] = fminf(fmaxf(acc, 0.f), 1.f);
    }
    __syncthreads();
    if (j < NH2) {
        const float* wr = W2 + (size_t)(b * NH2 + j) * NH1;
        float acc = b2[b * NH2 + j];
        for (int k = 0; k < NH1; k++) acc += sh1n[k] * wr[k];
        sh2n[j] = fminf(fmaxf(acc, 0.f), 1.f);
    }
    __syncthreads();
    if (j == 0) {
        float acc = b3[b];
        for (int k = 0; k < NH2; k++) acc += sh2n[k] * W3[b * NH2 + k];
        out[i] = acc;
    }
}

extern "C" void kernel_launch(void* const* d_in, const int* in_sizes, int n_in,
                              void* d_out, int out_size, void* d_ws, size_t ws_size,
                              hipStream_t stream) {
    const float* x  = (const float*)d_in[0];
    const int* bidx = (const int*)d_in[1];
    const float* W1 = (const float*)d_in[2];
    const float* b1 = (const float*)d_in[3];
    const float* W2 = (const float*)d_in[4];
    const float* b2 = (const float*)d_in[5];
    const float* W3 = (const float*)d_in[6];
    const float* b3 = (const float*)d_in[7];
    float* out = (float*)d_out;

    if (ws_size >= (size_t)WS_NEED) {
        char* ws = (char*)d_ws;
        int*   meta  = (int*)(ws + META_OFF);
        int*   order = (int*)(ws + ORDER_OFF);
        uint4* W1f   = (uint4*)(ws + W1F_OFF);
        uint4* W2f   = (uint4*)(ws + W2F_OFF);

        k_countscan<<<1, 1024, 0, stream>>>(bidx, meta);
        k_scatter<<<BATCH / 1024, 1024, 0, stream>>>(bidx, meta, order);
        k_pack<<<(W1F_U4 + W2F_U4) / 256, 256, 0, stream>>>(W1, W2, W1f, W2f);
        fused_v5<<<GRIDX, 256, 0, stream>>>(x, meta, order,
                                            (const short*)W1f, (const short*)W2f,
                                            b1, b2, W3, b3, out);
    } else {
        naive_mlp<<<BATCH, 256, 0, stream>>>(x, bidx, W1, b1, W2, b2, W3, b3, out);
    }
}

// Round 6
// 269.726 us; speedup vs baseline: 1.2127x; 1.2127x over previous
//
#include <hip/hip_runtime.h>

#define INSZ   2048
#define NH1    256
#define NH2    64
#define NB     8
#define BATCH  16384

#define TS        64                 // rows per block-tile
#define MAXTILES  (BATCH / TS)       // 256 (worst case: all samples in one bucket)
#define GRIDX     (NB * MAXTILES)    // 2048, bkt = blockIdx & 7 -> XCD pin heuristic

// W1f: [bkt][kb(64)][cb(16)][lane(64)][8] bf16
#define W1F_U4   (NB * 64 * 16 * 64)        // 524288 uint4
#define W2F_U4   (NB * 8 * 4 * 64)          // 16384 uint4

// ws layout (bytes)
#define META_OFF  0                  // 32 ints: cnt[8], off[8], cursor[8]
#define ORDER_OFF 1024               // 16384 ints
#define W1F_OFF   (1024 + BATCH * 4)            // 66560
#define W2F_OFF   (W1F_OFF + W1F_U4 * 16)       // 8,455,168
#define WS_NEED   (W2F_OFF + W2F_U4 * 16)       // 8,717,312

typedef float f4  __attribute__((ext_vector_type(4)));
typedef float f32x4 __attribute__((ext_vector_type(4)));
typedef short bf16x8 __attribute__((ext_vector_type(8)));

__device__ __forceinline__ unsigned short f2bf(float f) {
    unsigned u = __float_as_uint(f);
    u += 0x7fffu + ((u >> 16) & 1u);   // RNE
    return (unsigned short)(u >> 16);
}
__device__ __forceinline__ float clamp01(float v) { return fminf(fmaxf(v, 0.0f), 1.0f); }
__device__ __forceinline__ unsigned pack2(float a, float b) {
    return (unsigned)f2bf(a) | ((unsigned)f2bf(b) << 16);
}

// async global -> LDS, 16 B per lane; LDS base wave-uniform
__device__ __forceinline__ void glds16(const short* gsrc, short* ldst) {
    __builtin_amdgcn_global_load_lds(
        (const __attribute__((address_space(1))) unsigned int*)gsrc,
        (__attribute__((address_space(3))) unsigned int*)ldst, 16, 0, 0);
}

// ============================ pre-pass kernels ============================

__global__ void k_countscan(const int* __restrict__ idx, int* __restrict__ meta) {
    __shared__ int scnt[NB];
    int t = threadIdx.x;
    if (t < NB) scnt[t] = 0;
    __syncthreads();
    int local[NB];
#pragma unroll
    for (int bb = 0; bb < NB; bb++) local[bb] = 0;
    for (int i = t; i < BATCH; i += 1024) {
        int b = idx[i];
#pragma unroll
        for (int bb = 0; bb < NB; bb++) local[bb] += (b == bb) ? 1 : 0;
    }
#pragma unroll
    for (int bb = 0; bb < NB; bb++) {
        int v = local[bb];
        v += __shfl_xor(v, 1);  v += __shfl_xor(v, 2);  v += __shfl_xor(v, 4);
        v += __shfl_xor(v, 8);  v += __shfl_xor(v, 16); v += __shfl_xor(v, 32);
        if ((t & 63) == 0) atomicAdd(&scnt[bb], v);
    }
    __syncthreads();
    if (t == 0) {
        int run = 0;
        for (int b = 0; b < NB; b++) {
            int c = scnt[b];
            meta[b]      = c;
            meta[8 + b]  = run;
            meta[16 + b] = run;   // scatter cursor
            run += c;
        }
    }
}

__global__ void k_scatter(const int* __restrict__ idx, int* __restrict__ meta,
                          int* __restrict__ order) {
    __shared__ int wcnt[16][NB];
    __shared__ int sbase[NB];
    int t = threadIdx.x;
    int i = blockIdx.x * 1024 + t;
    int b = idx[i];
    int wv = t >> 6, lane = t & 63;
    unsigned long long mymask = 0;
#pragma unroll
    for (int bb = 0; bb < NB; bb++) {
        unsigned long long m = __ballot(b == bb);
        if (b == bb) mymask = m;
        if (lane == bb) wcnt[wv][bb] = (int)__popcll(m);
    }
    int myrank = (int)__popcll(mymask & ((1ull << lane) - 1ull));
    __syncthreads();
    if (t < NB) {
        int sum = 0;
        for (int w2 = 0; w2 < 16; w2++) { int c = wcnt[w2][t]; wcnt[w2][t] = sum; sum += c; }
        sbase[t] = atomicAdd(&meta[16 + t], sum);
    }
    __syncthreads();
    order[sbase[b] + wcnt[wv][b] + myrank] = i;
}

// pack W1/W2 into per-lane MFMA B-fragment order (bf16)
__global__ void k_pack(const float* __restrict__ W1, const float* __restrict__ W2,
                       uint4* __restrict__ W1f, uint4* __restrict__ W2f) {
    int u = blockIdx.x * 256 + threadIdx.x;
    if (u < W1F_U4) {
        int lane = u & 63, cb = (u >> 6) & 15, kb = (u >> 10) & 63, bkt = u >> 16;
        int l15 = lane & 15, quad = lane >> 4;
        const float* p = W1 + (size_t)(bkt * NH1 + cb * 16 + l15) * INSZ + kb * 32 + quad * 8;
        f4 lo = *(const f4*)p, hi = *(const f4*)(p + 4);
        uint4 o;
        o.x = pack2(lo[0], lo[1]); o.y = pack2(lo[2], lo[3]);
        o.z = pack2(hi[0], hi[1]); o.w = pack2(hi[2], hi[3]);
        W1f[u] = o;
    } else {
        int v = u - W1F_U4;
        if (v >= W2F_U4) return;
        int lane = v & 63, cg2 = (v >> 6) & 3, kb2 = (v >> 8) & 7, bkt = v >> 11;
        int l15 = lane & 15, quad = lane >> 4;
        const float* p = W2 + (size_t)(bkt * NH2 + cg2 * 16 + l15) * NH1 + kb2 * 32 + quad * 8;
        f4 lo = *(const f4*)p, hi = *(const f4*)(p + 4);
        uint4 o;
        o.x = pack2(lo[0], lo[1]); o.y = pack2(lo[2], lo[3]);
        o.z = pack2(hi[0], hi[1]); o.w = pack2(hi[2], hi[3]);
        W2f[v] = o;
    }
}

// ============================ main fused kernel ============================
// 64 rows x 256 cols per block, 8 waves; wave (g = w&1, c = w>>1) owns a
// 32x64 tile (2 A-frags x 4 B-frags, 8 MFMA/step). W1 staged via glds dbuf
// (read once per block). x staged regs->bf16->LDS with 1-step lookahead,
// loads issued at step top and consumed before the barrier -> barrier drains
// only ~step-old glds (no long-latency stall). One barrier per K-step.

__global__ __launch_bounds__(512, 2) void fused_v6(
    const float* __restrict__ x, const int* __restrict__ meta,
    const int* __restrict__ order,
    const short* __restrict__ W1f, const short* __restrict__ W2f,
    const float* __restrict__ b1, const float* __restrict__ b2,
    const float* __restrict__ W3, const float* __restrict__ b3,
    float* __restrict__ out)
{
    const int bkt  = blockIdx.x & 7;
    const int base = (blockIdx.x >> 3) * TS;
    const int cnt  = meta[bkt];
    if (base >= cnt) return;
    const int off = meta[8 + bkt];

    __shared__ short sW[2][8192];        // 2 x 16 KB  W1 k-step image (frag order)
    __shared__ short sX[2][TS * 40];     // 2 x 5 KB   x k-step (bf16, stride 40)
    __shared__ short sh1[TS * 264];      // 33.8 KB    h1 (bf16)
    __shared__ float sPart[2][TS];

    const int t = threadIdx.x;
    const int lane = t & 63, w = t >> 6;
    const int l15 = lane & 15, quad = lane >> 4;
    const int g = w & 1, c = w >> 1;     // row-group (32), col-group (64)

    // x staging: thread t -> row t>>3, 4 floats at (t&7)*4
    const int xr = t >> 3, kq = t & 7;
    int ir = base + xr; if (ir > cnt - 1) ir = cnt - 1;
    const float* xtp = x + (size_t)order[off + ir] * INSZ + kq * 4;
    const int sxo = xr * 40 + kq * 4;

    const short* wtile = W1f + ((size_t)bkt << 19);   // bkt * 64*8192 shorts

    f32x4 acc[2][4];
#pragma unroll
    for (int a = 0; a < 2; a++)
#pragma unroll
        for (int i = 0; i < 4; i++) acc[a][i] = (f32x4)0.0f;

    // ---- prologue: stage step 0 ----
    glds16(wtile + (2 * w)     * 512 + lane * 8, &sW[0][(2 * w)     * 512]);
    glds16(wtile + (2 * w + 1) * 512 + lane * 8, &sW[0][(2 * w + 1) * 512]);
    {
        f4 xv = *(const f4*)xtp;
        uint2 pk; pk.x = pack2(xv[0], xv[1]); pk.y = pack2(xv[2], xv[3]);
        *(uint2*)&sX[0][sxo] = pk;
    }
    __syncthreads();

#pragma unroll 1
    for (int kb = 0; kb < 64; kb++) {
        const int p = kb & 1;
        f4 xn;
        if (kb < 63) {
            // issue next-step loads FIRST: they age the whole step before use
            const short* gw = wtile + (size_t)(kb + 1) * 8192;
            glds16(gw + (2 * w)     * 512 + lane * 8, &sW[p ^ 1][(2 * w)     * 512]);
            glds16(gw + (2 * w + 1) * 512 + lane * 8, &sW[p ^ 1][(2 * w + 1) * 512]);
            xn = *(const f4*)(xtp + (kb + 1) * 32);
        }

        bf16x8 a0 = *(const bf16x8*)&sX[p][(g * 32 + l15)      * 40 + quad * 8];
        bf16x8 a1 = *(const bf16x8*)&sX[p][(g * 32 + 16 + l15) * 40 + quad * 8];
#pragma unroll
        for (int i = 0; i < 4; i++) {
            bf16x8 bf = *(const bf16x8*)&sW[p][((c * 4 + i) * 64 + lane) * 8];
            acc[0][i] = __builtin_amdgcn_mfma_f32_16x16x32_bf16(a0, bf, acc[0][i], 0, 0, 0);
            acc[1][i] = __builtin_amdgcn_mfma_f32_16x16x32_bf16(a1, bf, acc[1][i], 0, 0, 0);
        }

        if (kb < 63) {
            // consume x regs before the barrier: nothing long-latency outstanding
            uint2 pk; pk.x = pack2(xn[0], xn[1]); pk.y = pack2(xn[2], xn[3]);
            *(uint2*)&sX[p ^ 1][sxo] = pk;
        }
        __syncthreads();
    }

    // ---- layer-1 epilogue: bias + clip01 -> sh1 ----
#pragma unroll
    for (int i = 0; i < 4; i++) {
        int col = c * 64 + i * 16 + l15;
        float bias = b1[bkt * NH1 + col];
#pragma unroll
        for (int a = 0; a < 2; a++)
#pragma unroll
            for (int r = 0; r < 4; r++) {
                int row = g * 32 + a * 16 + quad * 4 + r;
                sh1[row * 264 + col] = (short)f2bf(clamp01(acc[a][i][r] + bias));
            }
    }
    __syncthreads();

    // ---- layer 2: wave w -> h2 rows (w&3)*16..+15, cols (w>>2)*32..+31 ----
    const int rw = w & 3, ch2 = w >> 2;
    f32x4 c2[2];
    c2[0] = (f32x4)0.0f; c2[1] = (f32x4)0.0f;
    const short* w2p = W2f + (size_t)bkt * 16384 + lane * 8;
#pragma unroll
    for (int kb2 = 0; kb2 < 8; kb2++) {
        bf16x8 a2 = *(const bf16x8*)&sh1[(rw * 16 + l15) * 264 + kb2 * 32 + quad * 8];
#pragma unroll
        for (int j = 0; j < 2; j++) {
            bf16x8 bw = *(const bf16x8*)(w2p + (kb2 * 4 + ch2 * 2 + j) * 512);
            c2[j] = __builtin_amdgcn_mfma_f32_16x16x32_bf16(a2, bw, c2[j], 0, 0, 0);
        }
    }

    // ---- layer-2 epilogue + layer-3 partial dot ----
    float s[4] = {0, 0, 0, 0};
#pragma unroll
    for (int j = 0; j < 2; j++) {
        int n2 = (ch2 * 2 + j) * 16 + l15;
        float bias2 = b2[bkt * NH2 + n2];
        float w3v   = W3[bkt * NH2 + n2];
#pragma unroll
        for (int r = 0; r < 4; r++)
            s[r] += clamp01(c2[j][r] + bias2) * w3v;
    }
#pragma unroll
    for (int r = 0; r < 4; r++) {
        float pp = s[r];
        pp += __shfl_xor(pp, 1); pp += __shfl_xor(pp, 2);
        pp += __shfl_xor(pp, 4); pp += __shfl_xor(pp, 8);
        if (l15 == 0) sPart[ch2][rw * 16 + quad * 4 + r] = pp;
    }
    __syncthreads();
    if (t < TS && base + t < cnt)
        out[order[off + base + t]] = sPart[0][t] + sPart[1][t] + b3[bkt];
}

// ============================ naive fallback ============================

__global__ void naive_mlp(const float* __restrict__ x, const int* __restrict__ idx,
                          const float* __restrict__ W1, const float* __restrict__ b1,
                          const float* __restrict__ W2, const float* __restrict__ b2,
                          const float* __restrict__ W3, const float* __restrict__ b3,
                          float* __restrict__ out)
{
    int i = blockIdx.x;
    int b = idx[i];
    __shared__ float sx[INSZ];
    __shared__ float sh1n[NH1];
    __shared__ float sh2n[NH2];
    for (int t = threadIdx.x; t < INSZ; t += 256) sx[t] = x[(size_t)i * INSZ + t];
    __syncthreads();
    int j = threadIdx.x;
    {
        const float* wr = W1 + (size_t)(b * NH1 + j) * INSZ;
        float acc = b1[b * NH1 + j];
        for (int k = 0; k < INSZ; k++) acc += sx[k] * wr[k];
        sh1n[j] = fminf(fmaxf(acc, 0.f), 1.f);
    }
    __syncthreads();
    if (j < NH2) {
        const float* wr = W2 + (size_t)(b * NH2 + j) * NH1;
        float acc = b2[b * NH2 + j];
        for (int k = 0; k < NH1; k++) acc += sh1n[k] * wr[k];
        sh2n[j] = fminf(fmaxf(acc, 0.f), 1.f);
    }
    __syncthreads();
    if (j == 0) {
        float acc = b3[b];
        for (int k = 0; k < NH2; k++) acc += sh2n[k] * W3[b * NH2 + k];
        out[i] = acc;
    }
}

extern "C" void kernel_launch(void* const* d_in, const int* in_sizes, int n_in,
                              void* d_out, int out_size, void* d_ws, size_t ws_size,
                              hipStream_t stream) {
    const float* x  = (const float*)d_in[0];
    const int* bidx = (const int*)d_in[1];
    const float* W1 = (const float*)d_in[2];
    const float* b1 = (const float*)d_in[3];
    const float* W2 = (const float*)d_in[4];
    const float* b2 = (const float*)d_in[5];
    const float* W3 = (const float*)d_in[6];
    const float* b3 = (const float*)d_in[7];
    float* out = (float*)d_out;

    if (ws_size >= (size_t)WS_NEED) {
        char* ws = (char*)d_ws;
        int*   meta  = (int*)(ws + META_OFF);
        int*   order = (int*)(ws + ORDER_OFF);
        uint4* W1f   = (uint4*)(ws + W1F_OFF);
        uint4* W2f   = (uint4*)(ws + W2F_OFF);

        k_countscan<<<1, 1024, 0, stream>>>(bidx, meta);
        k_scatter<<<BATCH / 1024, 1024, 0, stream>>>(bidx, meta, order);
        k_pack<<<(W1F_U4 + W2F_U4) / 256, 256, 0, stream>>>(W1, W2, W1f, W2f);
        fused_v6<<<GRIDX, 512, 0, stream>>>(x, meta, order,
                                            (const short*)W1f, (const short*)W2f,
                                            b1, b2, W3, b3, out);
    } else {
        naive_mlp<<<BATCH, 256, 0, stream>>>(x, bidx, W1, b1, W2, b2, W3, b3, out);
    }
}